// Round 2
// baseline (14989.140 us; speedup 1.0000x reference)
//
#include <hip/hip_runtime.h>

#define Bz 32
#define Tz 512
#define Dz 512
#define Lz 1024
#define Mz 10
#define G4D (4*Dz)      // 2048
#define KTOT (3*Dz)     // 1536 = [x_t ; ctx ; h]
#define KC 128
#define NKC 12          // KTOT/KC
#define JT 128
#define NJT 16          // G4D/JT

__device__ __forceinline__ float fsig(float x) { return 1.0f / (1.0f + __expf(-x)); }

// ---------------- K1: gates GEMM partials ----------------
// partial[kc][b][j] = sum_{k in chunk kc} Xhat[b][k] * W[j][k]
// Xhat = [x_t (512) ; ctx (512) ; h (512)], W = [W_ih | W_hh] rows j=0..2047
__global__ __launch_bounds__(256) void k_gemm(
    const float* __restrict__ x_all, const float* __restrict__ ctxs,
    const float* __restrict__ h, const float* __restrict__ W_ih,
    const float* __restrict__ W_hh, float* __restrict__ partial, int t)
{
  __shared__ float Xs[Bz][KC+2];
  __shared__ float Ws[JT][KC+2];
  const int jt = blockIdx.x, kc = blockIdx.y;
  const int j0 = jt*JT, k0 = kc*KC;
  const int tid = threadIdx.x;

  // stage Xhat chunk [32][128]
  for (int i = tid; i < Bz*KC; i += 256) {
    int bb = i >> 7, kk = i & (KC-1);
    int k = k0 + kk;
    float v;
    if (k < Dz)        v = x_all[((size_t)bb*Tz + t)*Dz + k];
    else if (k < 2*Dz) v = ctxs[bb*Dz + (k - Dz)];
    else               v = h[bb*Dz + (k - 2*Dz)];
    Xs[bb][kk] = v;
  }
  // stage W tile [128][128]
  {
    const float* Wsrc; int ldw, col0;
    if (k0 < 2*Dz) { Wsrc = W_ih; ldw = 2*Dz; col0 = k0; }
    else           { Wsrc = W_hh; ldw = Dz;   col0 = k0 - 2*Dz; }
    for (int i = tid; i < JT*(KC/4); i += 256) {
      int jj = i >> 5, k4 = (i & 31) << 2;
      float4 v = *reinterpret_cast<const float4*>(
          &Wsrc[(size_t)(j0 + jj)*ldw + col0 + k4]);
      *reinterpret_cast<float2*>(&Ws[jj][k4])     = make_float2(v.x, v.y);
      *reinterpret_cast<float2*>(&Ws[jj][k4 + 2]) = make_float2(v.z, v.w);
    }
  }
  __syncthreads();

  // compute: thread owns 4 j (stride 32) x 4 b
  const int jg = tid & 31, bg = tid >> 5;
  const int bl = bg << 2;
  float acc[4][4] = {};
  #pragma unroll 4
  for (int k = 0; k < KC; k += 2) {
    float2 xv[4], wv[4];
    #pragma unroll
    for (int bb2 = 0; bb2 < 4; bb2++)
      xv[bb2] = *reinterpret_cast<const float2*>(&Xs[bl + bb2][k]);
    #pragma unroll
    for (int jj = 0; jj < 4; jj++)
      wv[jj] = *reinterpret_cast<const float2*>(&Ws[jg + (jj << 5)][k]);
    #pragma unroll
    for (int jj = 0; jj < 4; jj++)
      #pragma unroll
      for (int bb2 = 0; bb2 < 4; bb2++)
        acc[jj][bb2] += wv[jj].x * xv[bb2].x + wv[jj].y * xv[bb2].y;
  }
  #pragma unroll
  for (int jj = 0; jj < 4; jj++)
    #pragma unroll
    for (int bb2 = 0; bb2 < 4; bb2++)
      partial[((size_t)kc*Bz + (bl + bb2))*G4D + j0 + jg + (jj << 5)] = acc[jj][bb2];
}

// ---------------- K2: reduce + LSTM + GMM params + truncated attention ----------------
__global__ __launch_bounds__(256) void k_fused(
    const float* __restrict__ partial, const float* __restrict__ b_ih,
    const float* __restrict__ b_hh, float* __restrict__ h, float* __restrict__ c,
    const float* __restrict__ W_g, const float* __restrict__ b_g,
    const float* __restrict__ memory, const int* __restrict__ lens,
    float* __restrict__ ctxs, float* __restrict__ ctx_out,
    float* __restrict__ align_out, float* __restrict__ term_out,
    int t, int final_)
{
  const int b = blockIdx.x, tid = threadIdx.x;
  __shared__ float gs[G4D];          // 8 KB gates
  __shared__ float hs[Dz];           // 2 KB h_new
  __shared__ float phis[3*Mz];
  __shared__ float prm[3*Mz];        // ksi, 1/beta, alpha
  __shared__ float wsm[Lz];          // 4 KB (only active range touched)
  __shared__ int   rng[2];

  // 1. reduce K-split partials + biases
  for (int j = tid; j < G4D; j += 256) {
    float s = b_ih[j] + b_hh[j];
    #pragma unroll
    for (int kc = 0; kc < NKC; kc++)
      s += partial[((size_t)kc*Bz + b)*G4D + j];
    gs[j] = s;
  }
  __syncthreads();

  // 2. LSTM pointwise (precise math: 512-step recurrence)
  for (int d = tid; d < Dz; d += 256) {
    float ig = 1.0f / (1.0f + expf(-gs[d]));
    float fg = 1.0f / (1.0f + expf(-gs[Dz + d]));
    float gg = tanhf(gs[2*Dz + d]);
    float og = 1.0f / (1.0f + expf(-gs[3*Dz + d]));
    float cn = fg * c[b*Dz + d] + ig * gg;
    float hn = og * tanhf(cn);
    c[b*Dz + d] = cn;
    h[b*Dz + d] = hn;
    hs[d] = hn;
  }
  __syncthreads();

  // 3. phi[m] = hs . W_g[m,:] + b_g[m]  (8 lanes per m, 30 m)
  if (tid < 8*3*Mz) {
    int m = tid >> 3, l8 = tid & 7;
    float s = 0.f;
    for (int k = l8; k < Dz; k += 8) s += W_g[m*Dz + k] * hs[k];
    s += __shfl_xor(s, 1);
    s += __shfl_xor(s, 2);
    s += __shfl_xor(s, 4);
    if (l8 == 0) phis[m] = s + b_g[m];
  }
  __syncthreads();

  // 4. GMM params + active l-range (serial, 10 mixtures - trivial)
  if (tid == 0) {
    float mx = -1e30f;
    #pragma unroll
    for (int m = 0; m < Mz; m++) mx = fmaxf(mx, phis[2*Mz + m]);
    float ae[Mz], ssum = 0.f;
    #pragma unroll
    for (int m = 0; m < Mz; m++) { ae[m] = expf(phis[2*Mz + m] - mx); ssum += ae[m]; }
    float lo = 1e30f, hi = -1e30f;
    #pragma unroll
    for (int m = 0; m < Mz; m++) {
      float ks = expf(phis[m]);
      float be = expf(phis[Mz + m]);
      prm[m]        = ks;
      prm[Mz + m]   = expf(-phis[Mz + m]);   // 1/beta
      prm[2*Mz + m] = ae[m] / ssum;          // alpha
      lo = fminf(lo, ks - 0.5f - 25.f*be);   // sig(-25)~1.4e-11: below fp32 visibility
      hi = fmaxf(hi, ks + 0.5f + 25.f*be);
    }
    int llo = lo > 0.f ? (int)floorf(lo) : 0;
    if (llo > Lz) llo = Lz;
    int lhi = hi < (float)Lz ? (int)ceilf(hi) + 1 : Lz;
    if (lhi > Lz) lhi = Lz;
    rng[0] = llo; rng[1] = lhi;
  }
  __syncthreads();

  const int llo = rng[0], lhi = rng[1];

  // 5. w on active range; write alignment (rest pre-zeroed once per call)
  for (int l = llo + tid; l < lhi; l += 256) {
    float u = (float)l;
    float t1 = 0.f, t0 = 0.f;
    #pragma unroll
    for (int m = 0; m < Mz; m++) {
      float ks = prm[m], ib = prm[Mz + m], al = prm[2*Mz + m];
      t1 += al * fsig((u + 0.5f - ks) * ib);
      t0 += al * fsig((u - 0.5f - ks) * ib);
    }
    float w = t1 - t0;
    wsm[l] = w;
    align_out[((size_t)b*Tz + t)*Lz + l] = w;
  }
  __syncthreads();

  // 6. ctx = sum_{l in range} w[l] * memory[b,l,:]   (thread owns d=tid, tid+256)
  {
    const float* mb = memory + (size_t)b*Lz*Dz;
    float acc0 = 0.f, acc1 = 0.f;
    for (int l = llo; l < lhi; l++) {
      float w = wsm[l];
      acc0 += w * mb[(size_t)l*Dz + tid];
      acc1 += w * mb[(size_t)l*Dz + tid + 256];
    }
    ctxs[b*Dz + tid]       = acc0;
    ctxs[b*Dz + tid + 256] = acc1;
    if (final_) {
      ctx_out[b*Dz + tid]       = acc0;
      ctx_out[b*Dz + tid + 256] = acc1;
    }
  }

  // 7. termination = 1 - t1 at l = lens[b]-1, last step only (exact, outside range ok)
  if (final_ && tid == 0) {
    float u = (float)(lens[b] - 1);
    float t1 = 0.f;
    #pragma unroll
    for (int m = 0; m < Mz; m++)
      t1 += prm[2*Mz + m] * fsig((u + 0.5f - prm[m]) * prm[Mz + m]);
    term_out[b] = 1.0f - t1;
  }
}

extern "C" void kernel_launch(void* const* d_in, const int* in_sizes, int n_in,
                              void* d_out, int out_size, void* d_ws, size_t ws_size,
                              hipStream_t stream)
{
  (void)in_sizes; (void)n_in; (void)out_size; (void)ws_size;
  const float* x    = (const float*)d_in[0];
  const float* mem  = (const float*)d_in[1];
  const int*   lens = (const int*)d_in[2];
  const float* W_ih = (const float*)d_in[3];
  const float* W_hh = (const float*)d_in[4];
  const float* b_ih = (const float*)d_in[5];
  const float* b_hh = (const float*)d_in[6];
  const float* W_g  = (const float*)d_in[7];
  const float* b_g  = (const float*)d_in[8];

  float* out = (float*)d_out;
  float* ctx_out   = out;                                  // [B,1,D]
  float* align_out = out + Bz*Dz;                          // [B,T,L]
  float* term_out  = out + Bz*Dz + (size_t)Bz*Tz*Lz;       // [B,1]

  float* wsf     = (float*)d_ws;
  float* h       = wsf;                 // [B,D]
  float* c       = h + Bz*Dz;           // [B,D]
  float* ctxs    = c + Bz*Dz;           // [B,D]
  float* partial = ctxs + Bz*Dz;        // [NKC][B][4D]

  // zero recurrent state; zero alignment output once (truncated support writes
  // only the active range per step)
  hipMemsetAsync(d_ws, 0, (size_t)(3*Bz*Dz)*sizeof(float), stream);
  hipMemsetAsync(align_out, 0, (size_t)Bz*Tz*Lz*sizeof(float), stream);

  for (int t = 0; t < Tz; t++) {
    k_gemm<<<dim3(NJT, NKC), 256, 0, stream>>>(x, ctxs, h, W_ih, W_hh, partial, t);
    k_fused<<<Bz, 256, 0, stream>>>(partial, b_ih, b_hh, h, c, W_g, b_g,
                                    mem, lens, ctxs, ctx_out, align_out, term_out,
                                    t, t == Tz-1);
  }
}

// Round 3
// 11615.088 us; speedup vs baseline: 1.2905x; 1.2905x over previous
//
#include <hip/hip_runtime.h>

#define Bz 32
#define Tz 512
#define Dz 512
#define Lz 1024
#define Mz 10
#define G4D (4*Dz)      // 2048
#define KC 128
#define JT 128
// k_pre tiles
#define PM 128
#define PN 128
#define PK 32

__device__ __forceinline__ float fsig(float x) { return 1.0f / (1.0f + __expf(-x)); }

// ---------------- K0 (once): xw[bt][j] = x[bt,:] . W_ih[j,0:512] + b_ih[j] + b_hh[j] ----------------
__global__ __launch_bounds__(256) void k_pre(
    const float* __restrict__ x, const float* __restrict__ W_ih,
    const float* __restrict__ b_ih, const float* __restrict__ b_hh,
    float* __restrict__ xw)
{
  __shared__ float As[PM][PK+1];
  __shared__ float Bs[PN][PK+1];
  const int m0 = blockIdx.x*PM, n0 = blockIdx.y*PN;
  const int tid = threadIdx.x;
  const int mg = tid >> 4, ng = tid & 15;
  float acc[8][8] = {};
  for (int k0 = 0; k0 < Dz; k0 += PK) {
    for (int i = tid; i < PM*(PK/4); i += 256) {
      int row = i >> 3, c4 = (i & 7) << 2;
      float4 v = *reinterpret_cast<const float4*>(&x[(size_t)(m0+row)*Dz + k0 + c4]);
      As[row][c4] = v.x; As[row][c4+1] = v.y; As[row][c4+2] = v.z; As[row][c4+3] = v.w;
    }
    for (int i = tid; i < PN*(PK/4); i += 256) {
      int row = i >> 3, c4 = (i & 7) << 2;
      float4 v = *reinterpret_cast<const float4*>(&W_ih[(size_t)(n0+row)*(2*Dz) + k0 + c4]);
      Bs[row][c4] = v.x; Bs[row][c4+1] = v.y; Bs[row][c4+2] = v.z; Bs[row][c4+3] = v.w;
    }
    __syncthreads();
    #pragma unroll 8
    for (int k = 0; k < PK; k++) {
      float a8[8], b8[8];
      #pragma unroll
      for (int r = 0; r < 8; r++) a8[r] = As[mg*8+r][k];
      #pragma unroll
      for (int s = 0; s < 8; s++) b8[s] = Bs[ng*8+s][k];
      #pragma unroll
      for (int r = 0; r < 8; r++)
        #pragma unroll
        for (int s = 0; s < 8; s++) acc[r][s] += a8[r]*b8[s];
    }
    __syncthreads();
  }
  #pragma unroll
  for (int r = 0; r < 8; r++) {
    int m = m0 + mg*8 + r;
    #pragma unroll
    for (int s = 0; s < 8; s++) {
      int n = n0 + ng*8 + s;
      xw[(size_t)m*G4D + n] = acc[r][s] + b_ih[n] + b_hh[n];
    }
  }
}

// ---------------- K1: gates GEMM partials over K = [kbase, 1536) ----------------
// Xhat = [x_t (512) ; ctx (512) ; h (512)], W = [W_ih | W_hh] rows j=0..2047
__global__ __launch_bounds__(256) void k_gemm(
    const float* __restrict__ x_all, const float* __restrict__ ctxs,
    const float* __restrict__ h, const float* __restrict__ W_ih,
    const float* __restrict__ W_hh, float* __restrict__ partial, int t, int kbase)
{
  __shared__ float Xs[Bz][KC+2];
  __shared__ float Ws[JT][KC+2];
  const int jt = blockIdx.x, kc = blockIdx.y;
  const int j0 = jt*JT, k0 = kbase + kc*KC;
  const int tid = threadIdx.x;

  for (int i = tid; i < Bz*KC; i += 256) {
    int bb = i >> 7, kk = i & (KC-1);
    int k = k0 + kk;
    float v;
    if (k < Dz)        v = x_all[((size_t)bb*Tz + t)*Dz + k];
    else if (k < 2*Dz) v = ctxs[bb*Dz + (k - Dz)];
    else               v = h[bb*Dz + (k - 2*Dz)];
    Xs[bb][kk] = v;
  }
  {
    const float* Wsrc; int ldw, col0;
    if (k0 < 2*Dz) { Wsrc = W_ih; ldw = 2*Dz; col0 = k0; }
    else           { Wsrc = W_hh; ldw = Dz;   col0 = k0 - 2*Dz; }
    for (int i = tid; i < JT*(KC/4); i += 256) {
      int jj = i >> 5, k4 = (i & 31) << 2;
      float4 v = *reinterpret_cast<const float4*>(
          &Wsrc[(size_t)(j0 + jj)*ldw + col0 + k4]);
      *reinterpret_cast<float2*>(&Ws[jj][k4])     = make_float2(v.x, v.y);
      *reinterpret_cast<float2*>(&Ws[jj][k4 + 2]) = make_float2(v.z, v.w);
    }
  }
  __syncthreads();

  const int jg = tid & 31, bg = tid >> 5;
  const int bl = bg << 2;
  float acc[4][4] = {};
  #pragma unroll 4
  for (int k = 0; k < KC; k += 2) {
    float2 xv[4], wv[4];
    #pragma unroll
    for (int bb2 = 0; bb2 < 4; bb2++)
      xv[bb2] = *reinterpret_cast<const float2*>(&Xs[bl + bb2][k]);
    #pragma unroll
    for (int jj = 0; jj < 4; jj++)
      wv[jj] = *reinterpret_cast<const float2*>(&Ws[jg + (jj << 5)][k]);
    #pragma unroll
    for (int jj = 0; jj < 4; jj++)
      #pragma unroll
      for (int bb2 = 0; bb2 < 4; bb2++)
        acc[jj][bb2] += wv[jj].x * xv[bb2].x + wv[jj].y * xv[bb2].y;
  }
  #pragma unroll
  for (int jj = 0; jj < 4; jj++)
    #pragma unroll
    for (int bb2 = 0; bb2 < 4; bb2++)
      partial[((size_t)kc*Bz + (bl + bb2))*G4D + j0 + jg + (jj << 5)] = acc[jj][bb2];
}

// ---------------- K2: reduce + LSTM + GMM params + truncated attention ----------------
__global__ __launch_bounds__(512) void k_fused(
    const float* __restrict__ partial, const float* __restrict__ b_ih,
    const float* __restrict__ b_hh, const float* __restrict__ xw,
    float* __restrict__ h, float* __restrict__ c,
    const float* __restrict__ W_g, const float* __restrict__ b_g,
    const float* __restrict__ memory, const int* __restrict__ lens,
    float* __restrict__ ctxs, float* __restrict__ ctx_out,
    float* __restrict__ align_out, float* __restrict__ term_out,
    int t, int final_, int nkc)
{
  const int b = blockIdx.x, tid = threadIdx.x;
  __shared__ float4 gs4[G4D/4];      // 8 KB gates
  __shared__ float hs[Dz];           // 2 KB
  __shared__ float phis[3*Mz];
  __shared__ float prm[3*Mz];        // ksi, 1/beta, alpha
  __shared__ float wsm[Lz];          // 4 KB (only active range touched)
  __shared__ int   rng[2];
  float* gs = (float*)gs4;

  // 1. gates = base + sum of K-split partials   (j4 = tid, exactly 512 float4s)
  {
    float4 s;
    if (xw) {
      s = *reinterpret_cast<const float4*>(&xw[((size_t)b*Tz + t)*G4D + 4*tid]);
    } else {
      int j = 4*tid;
      float4 bi = *reinterpret_cast<const float4*>(&b_ih[j]);
      float4 bh = *reinterpret_cast<const float4*>(&b_hh[j]);
      s = make_float4(bi.x+bh.x, bi.y+bh.y, bi.z+bh.z, bi.w+bh.w);
    }
    const float4* pp = reinterpret_cast<const float4*>(partial) + (size_t)b*(G4D/4) + tid;
    for (int kc = 0; kc < nkc; kc++) {
      float4 p = pp[(size_t)kc*Bz*(G4D/4)];
      s.x += p.x; s.y += p.y; s.z += p.z; s.w += p.w;
    }
    gs4[tid] = s;
  }
  __syncthreads();

  // 2. LSTM pointwise (d = tid), precise math for the 512-step recurrence
  {
    const int d = tid;
    float ig = 1.0f / (1.0f + expf(-gs[d]));
    float fg = 1.0f / (1.0f + expf(-gs[Dz + d]));
    float gg = tanhf(gs[2*Dz + d]);
    float og = 1.0f / (1.0f + expf(-gs[3*Dz + d]));
    float cn = fg * c[b*Dz + d] + ig * gg;
    float hn = og * tanhf(cn);
    c[b*Dz + d] = cn;
    h[b*Dz + d] = hn;
    hs[d] = hn;
  }
  __syncthreads();

  // 3. phi[m] = hs . W_g[m,:] + b_g[m]  (16 lanes per m, 30 m -> 480 threads)
  if (tid < 16*3*Mz) {
    int m = tid >> 4, l16 = tid & 15;
    float s = 0.f;
    #pragma unroll 4
    for (int k = l16; k < Dz; k += 16) s += W_g[m*Dz + k] * hs[k];
    s += __shfl_xor(s, 1);
    s += __shfl_xor(s, 2);
    s += __shfl_xor(s, 4);
    s += __shfl_xor(s, 8);
    if (l16 == 0) phis[m] = s + b_g[m];
  }
  __syncthreads();

  // 4. GMM params + active l-range (serial; 10 mixtures, trivial)
  if (tid == 0) {
    float mx = -1e30f;
    #pragma unroll
    for (int m = 0; m < Mz; m++) mx = fmaxf(mx, phis[2*Mz + m]);
    float ae[Mz], ssum = 0.f;
    #pragma unroll
    for (int m = 0; m < Mz; m++) { ae[m] = expf(phis[2*Mz + m] - mx); ssum += ae[m]; }
    float lo = 1e30f, hi = -1e30f;
    #pragma unroll
    for (int m = 0; m < Mz; m++) {
      float ks = expf(phis[m]);
      float be = expf(phis[Mz + m]);
      prm[m]        = ks;
      prm[Mz + m]   = expf(-phis[Mz + m]);   // 1/beta
      prm[2*Mz + m] = ae[m] / ssum;          // alpha
      lo = fminf(lo, ks - 0.5f - 25.f*be);   // sig(-25)~1.4e-11 < fp32 visibility
      hi = fmaxf(hi, ks + 0.5f + 25.f*be);
    }
    int llo = lo > 0.f ? (int)floorf(lo) : 0;
    if (llo > Lz) llo = Lz;
    int lhi = hi < (float)Lz ? (int)ceilf(hi) + 1 : Lz;
    if (lhi > Lz) lhi = Lz;
    rng[0] = llo; rng[1] = lhi;
  }
  __syncthreads();

  const int llo = rng[0], lhi = rng[1];

  // 5. w on active range; write alignment (rest pre-zeroed once per call)
  for (int l = llo + tid; l < lhi; l += 512) {
    float u = (float)l;
    float t1 = 0.f, t0 = 0.f;
    #pragma unroll
    for (int m = 0; m < Mz; m++) {
      float ks = prm[m], ib = prm[Mz + m], al = prm[2*Mz + m];
      t1 += al * fsig((u + 0.5f - ks) * ib);
      t0 += al * fsig((u - 0.5f - ks) * ib);
    }
    float w = t1 - t0;
    wsm[l] = w;
    align_out[((size_t)b*Tz + t)*Lz + l] = w;
  }
  __syncthreads();

  // 6. ctx = sum_{l in range} w[l] * memory[b,l,:]   (thread owns d = tid)
  {
    const float* mb = memory + (size_t)b*Lz*Dz + tid;
    float acc = 0.f;
    #pragma unroll 4
    for (int l = llo; l < lhi; l++)
      acc += wsm[l] * mb[(size_t)l*Dz];
    ctxs[b*Dz + tid] = acc;
    if (final_) ctx_out[b*Dz + tid] = acc;
  }

  // 7. termination = 1 - t1 at l = lens[b]-1, last step only (exact)
  if (final_ && tid == 0) {
    float u = (float)(lens[b] - 1);
    float t1 = 0.f;
    #pragma unroll
    for (int m = 0; m < Mz; m++)
      t1 += prm[2*Mz + m] * fsig((u + 0.5f - prm[m]) * prm[Mz + m]);
    term_out[b] = 1.0f - t1;
  }
}

extern "C" void kernel_launch(void* const* d_in, const int* in_sizes, int n_in,
                              void* d_out, int out_size, void* d_ws, size_t ws_size,
                              hipStream_t stream)
{
  (void)in_sizes; (void)n_in; (void)out_size;
  const float* x    = (const float*)d_in[0];
  const float* mem  = (const float*)d_in[1];
  const int*   lens = (const int*)d_in[2];
  const float* W_ih = (const float*)d_in[3];
  const float* W_hh = (const float*)d_in[4];
  const float* b_ih = (const float*)d_in[5];
  const float* b_hh = (const float*)d_in[6];
  const float* W_g  = (const float*)d_in[7];
  const float* b_g  = (const float*)d_in[8];

  float* out = (float*)d_out;
  float* ctx_out   = out;                                  // [B,1,D]
  float* align_out = out + Bz*Dz;                          // [B,T,L]
  float* term_out  = out + Bz*Dz + (size_t)Bz*Tz*Lz;       // [B,1]

  float* wsf     = (float*)d_ws;
  float* h       = wsf;                      // [B,D]
  float* c       = h + Bz*Dz;                // [B,D]
  float* ctxs    = c + Bz*Dz;                // [B,D]
  float* partial = wsf + 49152;              // up to [12][B][4D]
  float* xw      = partial + 12*Bz*G4D;      // [B*T][4D] (path A only)

  const size_t needA = ((size_t)49152 + 12*Bz*G4D + (size_t)Bz*Tz*G4D) * sizeof(float);
  const int useXW = (ws_size >= needA);
  const int nkc   = useXW ? 8 : 12;
  const int kbase = useXW ? Dz : 0;

  // zero recurrent state; zero alignment output once (truncated support writes
  // only the active range per step)
  hipMemsetAsync(d_ws, 0, (size_t)(3*Bz*Dz)*sizeof(float), stream);
  hipMemsetAsync(align_out, 0, (size_t)Bz*Tz*Lz*sizeof(float), stream);

  if (useXW)
    k_pre<<<dim3((Bz*Tz)/PM, G4D/PN), 256, 0, stream>>>(x, W_ih, b_ih, b_hh, xw);

  for (int t = 0; t < Tz; t++) {
    k_gemm<<<dim3(G4D/JT, nkc), 256, 0, stream>>>(x, ctxs, h, W_ih, W_hh, partial, t, kbase);
    k_fused<<<Bz, 512, 0, stream>>>(partial, b_ih, b_hh, useXW ? xw : nullptr,
                                    h, c, W_g, b_g, mem, lens, ctxs, ctx_out,
                                    align_out, term_out, t, t == Tz-1, nkc);
  }
}